// Round 9
// baseline (88.772 us; speedup 1.0000x reference)
//
#include <hip/hip_runtime.h>
#include <math.h>

#define T_TOK 4096
#define D_DIM 2048
#define E_EXP 8

typedef float f32x4 __attribute__((ext_vector_type(4)));

struct TokRec { int e0, e1; float g0, g1; };

// ---------------- Kernel 0: transpose Wg[d][e] -> WgT[e][d] (R5, validated) --
__global__ __launch_bounds__(256) void transpose_kernel(const float* __restrict__ Wg,
                                                        float* __restrict__ WgT) {
    const int d = blockIdx.x * 256 + threadIdx.x;
    const float4 a = *reinterpret_cast<const float4*>(Wg + (size_t)d * E_EXP);
    const float4 b = *reinterpret_cast<const float4*>(Wg + (size_t)d * E_EXP + 4);
    WgT[0 * D_DIM + d] = a.x;
    WgT[1 * D_DIM + d] = a.y;
    WgT[2 * D_DIM + d] = a.z;
    WgT[3 * D_DIM + d] = a.w;
    WgT[4 * D_DIM + d] = b.x;
    WgT[5 * D_DIM + d] = b.y;
    WgT[6 * D_DIM + d] = b.z;
    WgT[7 * D_DIM + d] = b.w;
}

// ---------------- Kernel 1: gating — EXACT R5 form (no LDS, high occupancy) --
__global__ __launch_bounds__(256) void gating_kernel(const float* __restrict__ x,
                                                     const float* __restrict__ WgT,
                                                     TokRec* __restrict__ recs) {
    const int wave = threadIdx.x >> 6;
    const int lane = threadIdx.x & 63;
    const int t = blockIdx.x * 4 + wave;
    const float* xr = x + (size_t)t * D_DIM;

    double acc[E_EXP];
#pragma unroll
    for (int e = 0; e < E_EXP; ++e) acc[e] = 0.0;
#pragma unroll
    for (int i = 0; i < D_DIM / 256; ++i) {
        const int d = i * 256 + lane * 4;
        const f32x4 xv = *reinterpret_cast<const f32x4*>(xr + d);
#pragma unroll
        for (int e = 0; e < E_EXP; ++e) {
            const f32x4 w = *reinterpret_cast<const f32x4*>(WgT + (size_t)e * D_DIM + d);
            acc[e] += (double)xv.x * (double)w.x + (double)xv.y * (double)w.y
                    + (double)xv.z * (double)w.z + (double)xv.w * (double)w.w;
        }
    }
#pragma unroll
    for (int e = 0; e < E_EXP; ++e) {
        double v = acc[e];
#pragma unroll
        for (int off = 32; off > 0; off >>= 1) v += __shfl_xor(v, off, 64);
        acc[e] = v;
    }
    if (lane == 0) {
        double m = acc[0];
#pragma unroll
        for (int e = 1; e < E_EXP; ++e) m = (acc[e] > m) ? acc[e] : m;
        double Z = 0.0;
#pragma unroll
        for (int e = 0; e < E_EXP; ++e) Z += exp(acc[e] - m);
        int e0 = 0;
#pragma unroll
        for (int e = 1; e < E_EXP; ++e) if (acc[e] > acc[e0]) e0 = e;
        int e1 = (e0 == 0) ? 1 : 0;
#pragma unroll
        for (int e = 0; e < E_EXP; ++e) if (e != e0 && acc[e] > acc[e1]) e1 = e;
        TokRec r;
        r.e0 = e0; r.e1 = e1;
        r.g0 = (float)(exp(acc[e0] - m) / Z);
        r.g1 = (float)(exp(acc[e1] - m) / Z);
        recs[t] = r;
    }
}

// ---------------- Kernel 2: redundant per-block scan + scatter (R8, validated)
// 512 blocks x 256 thr, 60 KB LDS -> 2 blocks/CU -> ALL blocks co-resident:
// the redundant scans run fully in parallel (one scan-time total), then each
// block writes its 64 contiguous rows + tags. No global smap round-trip.
__global__ __launch_bounds__(256) void scan_scatter_kernel(const float* __restrict__ x,
                                                           const TokRec* __restrict__ recs,
                                                           float* __restrict__ out_data,
                                                           float* __restrict__ out_tags,
                                                           float* __restrict__ out_loads) {
    __shared__ uint4 sb[256];
    __shared__ int offlds[256 * 8];
    __shared__ unsigned short ssrc[2 * T_TOK];
    __shared__ float sgate[2 * T_TOK];
    __shared__ int sloads[E_EXP];
    __shared__ int sbase[E_EXP];
    const int tid = threadIdx.x;

    const int t0 = tid * 16;
    unsigned long long c = 0ULL;
    TokRec rl[16];
    for (int k = 0; k < 16; ++k) {
        rl[k] = recs[t0 + k];
        c += 1ULL << (rl[k].e0 * 8);
        c += 1ULL << (rl[k].e1 * 8);
    }
    uint4 v;
    v.x = (unsigned)((c       ) & 0xFF) | ((unsigned)((c >>  8) & 0xFF) << 16);
    v.y = (unsigned)((c >> 16 ) & 0xFF) | ((unsigned)((c >> 24) & 0xFF) << 16);
    v.z = (unsigned)((c >> 32 ) & 0xFF) | ((unsigned)((c >> 40) & 0xFF) << 16);
    v.w = (unsigned)((c >> 48 ) & 0xFF) | ((unsigned)((c >> 56) & 0xFF) << 16);
    const uint4 own = v;
    sb[tid] = v;
    for (int d = 1; d < 256; d <<= 1) {
        __syncthreads();
        uint4 o = make_uint4(0u, 0u, 0u, 0u);
        if (tid >= d) o = sb[tid - d];
        __syncthreads();
        v.x += o.x; v.y += o.y; v.z += o.z; v.w += o.w;
        sb[tid] = v;
    }
    __syncthreads();
    if (tid == 0) {
        const uint4 tot = sb[255];
        int ld[8];
        ld[0] = (int)(tot.x & 0xFFFF); ld[1] = (int)(tot.x >> 16);
        ld[2] = (int)(tot.y & 0xFFFF); ld[3] = (int)(tot.y >> 16);
        ld[4] = (int)(tot.z & 0xFFFF); ld[5] = (int)(tot.z >> 16);
        ld[6] = (int)(tot.w & 0xFFFF); ld[7] = (int)(tot.w >> 16);
        int acc = 0;
#pragma unroll
        for (int e = 0; e < E_EXP; ++e) { sloads[e] = ld[e]; sbase[e] = acc; acc += ld[e]; }
    }
    __syncthreads();
    const int obase = tid * 8;
    offlds[obase + 0] = sbase[0] + (int)((v.x - own.x) & 0xFFFF);
    offlds[obase + 1] = sbase[1] + (int)((v.x - own.x) >> 16);
    offlds[obase + 2] = sbase[2] + (int)((v.y - own.y) & 0xFFFF);
    offlds[obase + 3] = sbase[3] + (int)((v.y - own.y) >> 16);
    offlds[obase + 4] = sbase[4] + (int)((v.z - own.z) & 0xFFFF);
    offlds[obase + 5] = sbase[5] + (int)((v.z - own.z) >> 16);
    offlds[obase + 6] = sbase[6] + (int)((v.w - own.w) & 0xFFFF);
    offlds[obase + 7] = sbase[7] + (int)((v.w - own.w) >> 16);
    for (int k = 0; k < 16; ++k) {
        const TokRec r = rl[k];
        const int tok = t0 + k;
        int d0 = offlds[obase + r.e0]++;
        ssrc[d0] = (unsigned short)tok;
        sgate[d0] = r.g0;
        int d1 = offlds[obase + r.e1]++;
        ssrc[d1] = (unsigned short)tok;
        sgate[d1] = r.g1;
    }
    __syncthreads();

    const int row0 = blockIdx.x * 64;
    const int e = row0 >> 12;
    const int le = sloads[e];
    const int be = sbase[e];

    if (tid < 64) {
        const int r = (row0 + tid) & (T_TOK - 1);
        out_tags[row0 + tid] = (r < le) ? (float)ssrc[be + r] : -1.0f;
    }
    if (blockIdx.x == 0 && tid < E_EXP) out_loads[tid] = (float)sloads[tid];

    const int col = tid * 8;
#pragma unroll 4
    for (int k = 0; k < 64; ++k) {
        const int row = row0 + k;
        const int r = row & (T_TOK - 1);
        float* orow = out_data + (size_t)row * D_DIM;
        if (r >= le) {
            const f32x4 z = {0.f, 0.f, 0.f, 0.f};
            *reinterpret_cast<f32x4*>(orow + col) = z;
            *reinterpret_cast<f32x4*>(orow + col + 4) = z;
        } else {
            const int src = (int)ssrc[be + r];
            const float g = sgate[be + r];
            const float* xr = x + (size_t)src * D_DIM;
            f32x4 a = *reinterpret_cast<const f32x4*>(xr + col);
            f32x4 b = *reinterpret_cast<const f32x4*>(xr + col + 4);
            a *= g;
            b *= g;
            *reinterpret_cast<f32x4*>(orow + col) = a;
            *reinterpret_cast<f32x4*>(orow + col + 4) = b;
        }
    }
}

extern "C" void kernel_launch(void* const* d_in, const int* in_sizes, int n_in,
                              void* d_out, int out_size, void* d_ws, size_t ws_size,
                              hipStream_t stream) {
    const float* x  = (const float*)d_in[0];
    const float* Wg = (const float*)d_in[1];

    float* out       = (float*)d_out;
    float* out_data  = out;
    float* out_tags  = out + (size_t)E_EXP * T_TOK * D_DIM;
    float* out_loads = out_tags + E_EXP * T_TOK;

    char* ws = (char*)d_ws;
    TokRec* recs = (TokRec*)ws;                 // 64 KiB
    float*  WgT  = (float*)(ws + 65536);        // 64 KiB

    transpose_kernel<<<D_DIM / 256, 256, 0, stream>>>(Wg, WgT);
    gating_kernel<<<T_TOK / 4, 256, 0, stream>>>(x, WgT, recs);
    scan_scatter_kernel<<<(E_EXP * T_TOK) / 64, 256, 0, stream>>>(x, recs, out_data, out_tags, out_loads);
}